// Round 1
// baseline (207.860 us; speedup 1.0000x reference)
//
#include <hip/hip_runtime.h>

#define N_NODES 50000
#define N_EDGES 800000
#define D 64

#define NPB 200                      // nodes per bucket
#define NB  250                      // buckets (NPB*NB == N_NODES)
#define CAP 4096                     // record capacity per bucket (mean 3200, 15.8 sigma)
#define GBLK 16                      // nodes per fused gather+linear block (= 1 MFMA tile)

#define HT 512                       // hist_h2b threads
#define HEPT 4                       // edges per thread (consecutive, int4 load)
#define HBLK ((N_EDGES + HT * HEPT - 1) / (HT * HEPT))   // 391 edge-histogram blocks

#define ST 256                       // scatter threads
#define SEPT 4                       // edges per thread (consecutive, int4 loads)
#define SBLK ((N_EDGES + ST * SEPT - 1) / (ST * SEPT))   // 782 scatter blocks

typedef unsigned short ushort_t;
typedef unsigned int   uint_t;
typedef __attribute__((ext_vector_type(8))) short   short8;
typedef __attribute__((ext_vector_type(4))) float   float4v;

// bf16 helpers (RNE down-convert; up-convert is exact)
__device__ __forceinline__ ushort_t f2b(float f) {
    uint_t u = __float_as_uint(f);
    return (ushort_t)((u + 0x7FFFu + ((u >> 16) & 1u)) >> 16);
}
__device__ __forceinline__ float b2f(ushort_t b) {
    return __uint_as_float((uint_t)b << 16);
}
// fp32 bits -> bf16 bits (RNE), kept in the HIGH 16 bits of a uint
__device__ __forceinline__ uint_t rne_hi16(uint_t u) {
    return (u + 0x7FFFu + ((u >> 16) & 1u)) & 0xFFFF0000u;
}
__device__ __forceinline__ float lane_bcast(float v, int l) {
    return __int_as_float(__builtin_amdgcn_readlane(__float_as_int(v), l));
}

// ---------------------------------------------------------------------------
// ws layout (16B-aligned sections):
//   pedges : uint[NB*CAP]     (4.10 MB) node-sorted records: src | (w_bf16<<16)
//   offs2  : int2[N_NODES]    (0.4 MB)  per-node (beg,end) into pedges
//   h_bf16 : ushort[N*D]      (6.4 MB)
//   cnt    : int[N_NODES]     (0.2 MB)  per-node in-degree (memset 0)
//   ncur   : int[N_NODES]     (0.2 MB)  per-node scatter cursor (init by scan)
//
// Structure notes (evidence across sessions):
//  - sort-then-register-accumulate beats atomic float ACCUMULATION 3-6x
//    (that was 51M float atomics). Here atomics POSITION only: 1.6M int ops.
//  - gather is pinned at ~47 us: random-row transaction floor.
//  - R14: replaced two-phase counting sort (bedges round-trip, 32 barriers
//    per bin block, 391x250 serialized cursor tickets, second LDS sort at
//    250 blocks) with direct hist -> per-bucket scan -> atomic-cursor
//    scatter. Bucket-strided pedges/offs2 layout preserved so the gather
//    kernel is byte-identical to the proven 47 us version.
// ---------------------------------------------------------------------------

// ---------------- K1: per-node histogram (blocks < HBLK) + h->bf16 (rest) ------
__global__ __launch_bounds__(HT) void hist_h2b_kernel(
    const int* __restrict__ dst, int* __restrict__ cnt,
    const float* __restrict__ h, ushort_t* __restrict__ hb)
{
    if (blockIdx.x >= HBLK) {
        const int nb = gridDim.x - HBLK;
        for (int i = (blockIdx.x - HBLK) * HT + threadIdx.x;
             i < N_NODES * D / 4; i += nb * HT) {
            const float4 v = ((const float4*)h)[i];
            ushort4 o;
            o.x = f2b(v.x); o.y = f2b(v.y); o.z = f2b(v.z); o.w = f2b(v.w);
            ((ushort4*)hb)[i] = o;
        }
        return;
    }

    const int e0 = (blockIdx.x * HT + threadIdx.x) * HEPT;
    if (e0 + HEPT <= N_EDGES) {
        const int4 d4 = *(const int4*)(dst + e0);
        atomicAdd(&cnt[d4.x], 1);
        atomicAdd(&cnt[d4.y], 1);
        atomicAdd(&cnt[d4.z], 1);
        atomicAdd(&cnt[d4.w], 1);
    } else {
        for (int e = e0; e < N_EDGES; ++e) atomicAdd(&cnt[dst[e]], 1);
    }
}

// ---------------- K2: per-bucket exclusive scan -> offs2 + cursors ----------
__global__ __launch_bounds__(256) void bucket_scan_kernel(
    const int* __restrict__ cnt, int2* __restrict__ offs2,
    int* __restrict__ ncur)
{
    __shared__ int part[256];
    const int b = blockIdx.x;
    const int t = threadIdx.x;
    const int gb = b * CAP;

    const int v = (t < NPB) ? cnt[b * NPB + t] : 0;
    part[t] = v;
    __syncthreads();
    for (int off = 1; off < 256; off <<= 1) {
        int p = 0;
        if (t >= off) p = part[t - off];
        __syncthreads();
        part[t] += p;
        __syncthreads();
    }
    if (t < NPB) {
        const int ex  = part[t] - v;
        const int beg = gb + min(ex, CAP);
        const int end = gb + min(ex + v, CAP);
        offs2[b * NPB + t] = make_int2(beg, end);
        ncur[b * NPB + t]  = beg;
    }
}

// ---------------- K3: direct scatter to node-exact positions ----------------
__global__ __launch_bounds__(ST) void scatter_kernel(
    const int* __restrict__ src, const int* __restrict__ dst,
    const float* __restrict__ w, int* __restrict__ ncur,
    uint_t* __restrict__ pedges)
{
    const int e0 = (blockIdx.x * ST + threadIdx.x) * SEPT;
    if (e0 >= N_EDGES) return;

    if (e0 + SEPT <= N_EDGES) {
        const int4   s4 = *(const int4*)(src + e0);
        const int4   d4 = *(const int4*)(dst + e0);
        const float4 w4 = *(const float4*)(w + e0);
        const int   s[4]  = { s4.x, s4.y, s4.z, s4.w };
        const int   d[4]  = { d4.x, d4.y, d4.z, d4.w };
        const float ww[4] = { w4.x, w4.y, w4.z, w4.w };
        uint_t rec[4];
        int    p[4];
#pragma unroll
        for (int k = 0; k < SEPT; ++k)
            rec[k] = (uint_t)s[k] | rne_hi16(__float_as_uint(ww[k]));
#pragma unroll
        for (int k = 0; k < SEPT; ++k)
            p[k] = atomicAdd(&ncur[d[k]], 1);
#pragma unroll
        for (int k = 0; k < SEPT; ++k) {
            // overflow guard: never taken unless a bucket exceeds CAP (15.8 sigma)
            const int bend = (int)((unsigned)d[k] / NPB) * CAP + CAP;
            if (p[k] < bend) pedges[p[k]] = rec[k];
        }
    } else {
        for (int e = e0; e < N_EDGES; ++e) {
            const int dd = dst[e];
            const uint_t rec = (uint_t)src[e] | rne_hi16(__float_as_uint(w[e]));
            const int p = atomicAdd(&ncur[dd], 1);
            const int bend = (int)((unsigned)dd / NPB) * CAP + CAP;
            if (p < bend) pedges[p] = rec;
        }
    }
}

// ---------------- K4: fused gather (8 waves x 2 nodes, 16-deep) + MFMA linear ----
__global__ __launch_bounds__(512) void gather_linear_kernel(
    const ushort_t* __restrict__ hb, const uint_t* __restrict__ pedges,
    const int2* __restrict__ offs2,
    const float* __restrict__ Ws, const float* __restrict__ bs,
    const float* __restrict__ Wn, const float* __restrict__ bn,
    float* __restrict__ out)
{
    __shared__ ushort_t nstage[GBLK * D];   // 2 KB

    const int wave  = threadIdx.x >> 6;     // 0..7
    const int lane  = threadIdx.x & 63;
    const int node0 = blockIdx.x * GBLK;

    // ---- phase 1: 2 nodes per wave, 16-deep MLP ----
#pragma unroll
    for (int jj = 0; jj < 2; ++jj) {
        const int j = wave * 2 + jj;        // node-in-block 0..15
        const int node = node0 + j;
        if (node < N_NODES) {
            const int2 be = offs2[node];
            const int beg = be.x, end = be.y;
            float acc = 0.f;
            int e = beg;
            for (; e + 16 <= end; e += 16) {
                uint_t r[16];
                float  vv[16];
#pragma unroll
                for (int k = 0; k < 16; ++k) r[k] = pedges[e + k];
#pragma unroll
                for (int k = 0; k < 16; ++k)
                    vv[k] = b2f(hb[(size_t)(r[k] & 0xFFFFu) * D + lane]);
#pragma unroll
                for (int k = 0; k < 16; ++k)
                    acc = fmaf(__uint_as_float(r[k] & 0xFFFF0000u), vv[k], acc);
            }
            for (; e + 4 <= end; e += 4) {
                uint_t r[4];
                float  vv[4];
#pragma unroll
                for (int k = 0; k < 4; ++k) r[k] = pedges[e + k];
#pragma unroll
                for (int k = 0; k < 4; ++k)
                    vv[k] = b2f(hb[(size_t)(r[k] & 0xFFFFu) * D + lane]);
#pragma unroll
                for (int k = 0; k < 4; ++k)
                    acc = fmaf(__uint_as_float(r[k] & 0xFFFF0000u), vv[k], acc);
            }
            for (; e < end; ++e) {
                const uint_t r = pedges[e];
                acc = fmaf(__uint_as_float(r & 0xFFFF0000u),
                           b2f(hb[(size_t)(r & 0xFFFFu) * D + lane]), acc);
            }
            nstage[j * D + lane] = f2b(acc);
        }
    }
    __syncthreads();

    // ---- phase 2: waves 0-3, one 16-col tile each ----
    const int nt = wave;
    if (nt >= 4 || node0 >= N_NODES) return;
    const int row16 = lane & 15;
    const int quad  = lane >> 4;

    const size_t abase = (size_t)(node0 + row16) * D + quad * 8;
    const short8 ah0 = *(const short8*)(hb + abase);
    const short8 ah1 = *(const short8*)(hb + abase + 32);
    const ushort_t* sp = nstage + row16 * D + quad * 8;
    const short8 an0 = *(const short8*)sp;
    const short8 an1 = *(const short8*)(sp + 32);

    const int col = nt * 16 + row16;
    const float* wsr = Ws + (size_t)col * D + quad * 8;
    const float* wnr = Wn + (size_t)col * D + quad * 8;
    short8 bw[4];   // ws_k0, ws_k1, wn_k0, wn_k1
#pragma unroll
    for (int f = 0; f < 4; ++f) {
        const float* p = (f < 2 ? wsr : wnr) + (f & 1) * 32;
        const float4 w0 = *(const float4*)p;
        const float4 w1 = *(const float4*)(p + 4);
        short8 bwv;
        bwv[0] = (short)f2b(w0.x); bwv[1] = (short)f2b(w0.y);
        bwv[2] = (short)f2b(w0.z); bwv[3] = (short)f2b(w0.w);
        bwv[4] = (short)f2b(w1.x); bwv[5] = (short)f2b(w1.y);
        bwv[6] = (short)f2b(w1.z); bwv[7] = (short)f2b(w1.w);
        bw[f] = bwv;
    }
    float4v acc = {0.f, 0.f, 0.f, 0.f};
    acc = __builtin_amdgcn_mfma_f32_16x16x32_bf16(ah0, bw[0], acc, 0, 0, 0);
    acc = __builtin_amdgcn_mfma_f32_16x16x32_bf16(ah1, bw[1], acc, 0, 0, 0);
    acc = __builtin_amdgcn_mfma_f32_16x16x32_bf16(an0, bw[2], acc, 0, 0, 0);
    acc = __builtin_amdgcn_mfma_f32_16x16x32_bf16(an1, bw[3], acc, 0, 0, 0);

    const float bias = bs[col] + bn[col];
#pragma unroll
    for (int r = 0; r < 4; ++r) {
        const int m = quad * 4 + r;
        out[(size_t)(node0 + m) * D + col] = fmaxf(acc[r] + bias, 0.f);
    }
}

// ---------------- fallback path (ws too small): fp32 atomic scatter ----------------
__global__ __launch_bounds__(256) void sage_scatter(
    const float* __restrict__ h,
    const int* __restrict__ edge_src,
    const int* __restrict__ edge_dst,
    const float* __restrict__ edge_w,
    float* __restrict__ neigh)
{
    const long long tid = (long long)blockIdx.x * blockDim.x + threadIdx.x;
    const int e = (int)(tid >> 6);
    const int d = (int)(tid & 63);
    if (e >= N_EDGES) return;
    atomicAdd(&neigh[(long long)edge_dst[e] * D + d],
              edge_w[e] * h[(long long)edge_src[e] * D + d]);
}

__global__ __launch_bounds__(256, 2) void linear_f32_kernel(
    const float* __restrict__ h, const float* __restrict__ neigh,
    const float* __restrict__ Ws, const float* __restrict__ bs,
    const float* __restrict__ Wn, const float* __restrict__ bn,
    float* __restrict__ out)
{
    const int lane   = threadIdx.x & 63;
    const int gwave  = (blockIdx.x * blockDim.x + threadIdx.x) >> 6;
    const int nwaves = (gridDim.x * blockDim.x) >> 6;

    float Wsr[D], Wnr[D];
#pragma unroll
    for (int k = 0; k < D; k += 4) {
        const float4 a = *(const float4*)&Ws[(size_t)lane * D + k];
        const float4 b = *(const float4*)&Wn[(size_t)lane * D + k];
        Wsr[k] = a.x; Wsr[k+1] = a.y; Wsr[k+2] = a.z; Wsr[k+3] = a.w;
        Wnr[k] = b.x; Wnr[k+1] = b.y; Wnr[k+2] = b.z; Wnr[k+3] = b.w;
    }
    const float bias = bs[lane] + bn[lane];

    for (int n = gwave; n < N_NODES; n += nwaves) {
        const float hv = h[(size_t)n * D + lane];
        const float nv = neigh[(size_t)n * D + lane];
        float o = bias;
#pragma unroll
        for (int k = 0; k < D; ++k) {
            o = fmaf(lane_bcast(hv, k), Wsr[k], o);
            o = fmaf(lane_bcast(nv, k), Wnr[k], o);
        }
        out[(size_t)n * D + lane] = fmaxf(o, 0.f);
    }
}

extern "C" void kernel_launch(void* const* d_in, const int* in_sizes, int n_in,
                              void* d_out, int out_size, void* d_ws, size_t ws_size,
                              hipStream_t stream)
{
    const float* h        = (const float*)d_in[0];
    const int*   edge_src = (const int*)d_in[1];
    const int*   edge_dst = (const int*)d_in[2];
    const float* edge_w   = (const float*)d_in[3];
    const float* W_self   = (const float*)d_in[4];
    const float* b_self   = (const float*)d_in[5];
    const float* W_neigh  = (const float*)d_in[6];
    const float* b_neigh  = (const float*)d_in[7];
    float*       out      = (float*)d_out;

    // ws layout
    uint_t*   pedges = (uint_t*)d_ws;                             // NB*CAP uint
    int2*     offs2  = (int2*)(pedges + (size_t)NB * CAP);        // N_NODES int2
    ushort_t* hb     = (ushort_t*)(offs2 + N_NODES);              // N*D ushort
    int*      cnt    = (int*)(hb + (size_t)N_NODES * D);          // N_NODES int
    int*      ncur   = cnt + N_NODES;                             // N_NODES int
    const size_t needed = (size_t)NB * CAP * 4 + (size_t)N_NODES * 8
                        + (size_t)N_NODES * D * 2
                        + (size_t)N_NODES * 4 + (size_t)N_NODES * 4;

    if (ws_size >= needed) {
        hipMemsetAsync(cnt, 0, N_NODES * sizeof(int), stream);
        hist_h2b_kernel<<<HBLK * 2, HT, 0, stream>>>(edge_dst, cnt, h, hb);
        bucket_scan_kernel<<<NB, 256, 0, stream>>>(cnt, offs2, ncur);
        scatter_kernel<<<SBLK, ST, 0, stream>>>(edge_src, edge_dst, edge_w,
                                                ncur, pedges);
        gather_linear_kernel<<<(N_NODES + GBLK - 1) / GBLK, 512, 0, stream>>>(
            hb, pedges, offs2, W_self, b_self, W_neigh, b_neigh, out);
    } else {
        float* neigh_fb = (float*)d_ws;
        hipMemsetAsync(neigh_fb, 0, (size_t)N_NODES * D * sizeof(float), stream);
        const long long total = (long long)N_EDGES * 64;
        sage_scatter<<<(int)((total + 255) / 256), 256, 0, stream>>>(
            h, edge_src, edge_dst, edge_w, neigh_fb);
        linear_f32_kernel<<<1024, 256, 0, stream>>>(h, neigh_fb, W_self, b_self,
                                                    W_neigh, b_neigh, out);
    }
}

// Round 2
// 155.226 us; speedup vs baseline: 1.3391x; 1.3391x over previous
//
#include <hip/hip_runtime.h>

#define N_NODES 50000
#define N_EDGES 800000
#define D 64

#define NPB 200                      // nodes per bucket
#define NB  250                      // buckets (NPB*NB == N_NODES)
#define CAP 4096                     // record capacity per bucket (mean 3200, 15.8 sigma)
#define BT  256                      // threads for bin (4 waves) -- R15: was 512
#define EPT 4                        // edges per thread in bin
#define CHUNK_E (BT * EPT)           // 1024 edges per block
#define NCHUNKS ((N_EDGES + CHUNK_E - 1) / CHUNK_E)   // 782
#define CONVB 256                    // h->bf16 conversion blocks appended to bin grid
#define CT  1024                     // bucket_csr threads (16 waves)
#define GBLK 16                      // nodes per fused gather+linear block (= 1 MFMA tile)

typedef unsigned short ushort_t;
typedef unsigned int   uint_t;
typedef __attribute__((ext_vector_type(8))) short   short8;
typedef __attribute__((ext_vector_type(4))) float   float4v;

// bf16 helpers (RNE down-convert; up-convert is exact)
__device__ __forceinline__ ushort_t f2b(float f) {
    uint_t u = __float_as_uint(f);
    return (ushort_t)((u + 0x7FFFu + ((u >> 16) & 1u)) >> 16);
}
__device__ __forceinline__ float b2f(ushort_t b) {
    return __uint_as_float((uint_t)b << 16);
}
// fp32 bits -> bf16 bits (RNE), kept in the HIGH 16 bits of a uint
__device__ __forceinline__ uint_t rne_hi16(uint_t u) {
    return (u + 0x7FFFu + ((u >> 16) & 1u)) & 0xFFFF0000u;
}
__device__ __forceinline__ float lane_bcast(float v, int l) {
    return __int_as_float(__builtin_amdgcn_readlane(__float_as_int(v), l));
}

// ---------------------------------------------------------------------------
// ws layout (16B-aligned sections):
//   bedges : int2[NB*CAP]     (8.19 MB) bucket-grouped packed records (bin out)
//   pedges : uint[NB*CAP]     (4.10 MB) node-sorted records: src | (w_bf16<<16)
//   offs2  : int2[N_NODES]    (0.4 MB)  per-node (beg,end) into pedges
//   h_bf16 : ushort[N*D]      (6.4 MB)
//   cursor : int[NB]          (memset 0; bin rebases to b*CAP + old)
// Binned record: .x=(src<<8)|local_dst, .y=bits(w).
//
// Cost model (R14 post-mortem): measured dur includes the harness's 268 MB
// ws poison fill (~46.5 us, irreducible). R0 split: fill 46.5 + bin ~45 +
// csr ~4 + gather ~47 + memset ~2 = 145. R14's hist+atomic-scatter replaced
// the 4-us csr with a 50-us scatter (800k atomic-with-return ~ one 46-50 us
// "random pass" regardless of form) -> reverted.
// R15: bin is latency-bound, not throughput-bound: 391 blocks = 1.53/CU (no
// chain overlap) x ~22 barriers/block. Fix: 782 blocks of 256 thr (~4
// resident chains/CU) + shuffle-scan (5 barriers/block).
// ---------------------------------------------------------------------------

// ---------------- K1: bin edges by bucket (blocks < NCHUNKS) + h->bf16 (rest) ----
__global__ __launch_bounds__(BT) void bin_h2b_kernel(
    const int* __restrict__ src, const int* __restrict__ dst,
    const float* __restrict__ w, int* __restrict__ cursor,
    int2* __restrict__ bedges,
    const float* __restrict__ h, ushort_t* __restrict__ hb)
{
    if (blockIdx.x >= NCHUNKS) {
        const int nb = gridDim.x - NCHUNKS;
        for (int i = (blockIdx.x - NCHUNKS) * BT + threadIdx.x;
             i < N_NODES * D / 4; i += nb * BT) {
            const float4 v = ((const float4*)h)[i];
            ushort4 o;
            o.x = f2b(v.x); o.y = f2b(v.y); o.z = f2b(v.z); o.w = f2b(v.w);
            ((ushort4*)hb)[i] = o;
        }
        return;
    }

    __shared__ int lh[NB];
    __shared__ int loff[NB];
    __shared__ int lcur[NB];
    __shared__ int gpos[NB];
    __shared__ int wsum[4];
    __shared__ int2 stage[CHUNK_E];
    __shared__ unsigned char sbk[CHUNK_E];

    const int t = threadIdx.x;
    for (int i = t; i < NB; i += BT) lh[i] = 0;
    __syncthreads();

    const int base = blockIdx.x * CHUNK_E;
    int   my_b[EPT];
    int   my_p[EPT];
    float my_w[EPT];
#pragma unroll
    for (int k = 0; k < EPT; ++k) {
        const int e = base + k * BT + t;
        if (e < N_EDGES) {
            const int d = dst[e];
            const int b = (unsigned)d / NPB;
            my_b[k] = b;
            my_p[k] = (src[e] << 8) | (d - b * NPB);
            my_w[k] = w[e];
            atomicAdd(&lh[b], 1);
        } else {
            my_b[k] = -1;
        }
    }
    __syncthreads();

    // exclusive scan over 256 slots via wave shuffles (2 barriers, not 16)
    const int v    = (t < NB) ? lh[t] : 0;
    const int lane = t & 63;
    const int wid  = t >> 6;
    int inc = v;
#pragma unroll
    for (int dlt = 1; dlt < 64; dlt <<= 1) {
        const int n = __shfl_up(inc, dlt, 64);
        if (lane >= dlt) inc += n;
    }
    if (lane == 63) wsum[wid] = inc;
    __syncthreads();
    int wpre = 0;
#pragma unroll
    for (int i = 0; i < 3; ++i) wpre += (i < wid) ? wsum[i] : 0;
    const int ex = wpre + inc - v;
    if (t < NB) { loff[t] = ex; lcur[t] = ex; }
    __syncthreads();

#pragma unroll
    for (int k = 0; k < EPT; ++k) {
        if (my_b[k] >= 0) {
            const int p = atomicAdd(&lcur[my_b[k]], 1);
            stage[p] = make_int2(my_p[k], __float_as_int(my_w[k]));
            sbk[p] = (unsigned char)my_b[k];
        }
    }
    __syncthreads();

    if (t < NB && lh[t] > 0)
        gpos[t] = t * CAP + atomicAdd(&cursor[t], lh[t]);
    __syncthreads();

    const int tot = min(N_EDGES - base, CHUNK_E);
    for (int s = t; s < tot; s += BT) {
        const int b = sbk[s];
        bedges[gpos[b] + (s - loff[b])] = stage[s];
    }
}

// ---------------- K2: per-bucket node-exact CSR -> packed 4-B records ----------
__global__ __launch_bounds__(CT) void bucket_csr_kernel(
    const int* __restrict__ cursor, const int2* __restrict__ bedges,
    uint_t* __restrict__ pedges, int2* __restrict__ offs2)
{
    __shared__ int    lcur[NPB];
    __shared__ int    part[256];
    __shared__ uint_t stage[CAP];   // 16 KB

    const int b   = blockIdx.x;
    const int t   = threadIdx.x;
    const int gb  = b * CAP;
    const int cnt = min(cursor[b], CAP);

    // per-node histogram
    if (t < NPB) lcur[t] = 0;
    __syncthreads();
    for (int e = t; e < cnt; e += CT)
        atomicAdd(&lcur[bedges[gb + e].x & 255], 1);
    __syncthreads();

    // exclusive scan of NPB counts (first 256 threads)
    const int v = (t < NPB) ? lcur[t] : 0;
    if (t < 256) part[t] = v;
    __syncthreads();
    for (int off = 1; off < 256; off <<= 1) {
        int p = 0;
        if (t < 256 && t >= off) p = part[t - off];
        __syncthreads();
        if (t < 256) part[t] += p;
        __syncthreads();
    }
    if (t < NPB) {
        const int ex = part[t] - v;
        lcur[t] = ex;
        offs2[b * NPB + t] = make_int2(gb + ex, gb + ex + v);
    }
    __syncthreads();

    // position via LDS atomics, scatter PACKED into LDS stage
    for (int e = t; e < cnt; e += CT) {
        const int2 r = bedges[gb + e];
        const int p = atomicAdd(&lcur[r.x & 255], 1);
        stage[p] = (uint_t)(r.x >> 8) | rne_hi16((uint_t)r.y);
    }
    __syncthreads();
    // fully coalesced flush to pedges
    for (int s = t; s < cnt; s += CT)
        pedges[gb + s] = stage[s];
}

// ---------------- K3: fused gather (8 waves x 2 nodes, 16-deep) + MFMA linear ----
__global__ __launch_bounds__(512) void gather_linear_kernel(
    const ushort_t* __restrict__ hb, const uint_t* __restrict__ pedges,
    const int2* __restrict__ offs2,
    const float* __restrict__ Ws, const float* __restrict__ bs,
    const float* __restrict__ Wn, const float* __restrict__ bn,
    float* __restrict__ out)
{
    __shared__ ushort_t nstage[GBLK * D];   // 2 KB

    const int wave  = threadIdx.x >> 6;     // 0..7
    const int lane  = threadIdx.x & 63;
    const int node0 = blockIdx.x * GBLK;

    // ---- phase 1: 2 nodes per wave, 16-deep MLP ----
#pragma unroll
    for (int jj = 0; jj < 2; ++jj) {
        const int j = wave * 2 + jj;        // node-in-block 0..15
        const int node = node0 + j;
        if (node < N_NODES) {
            const int2 be = offs2[node];
            const int beg = be.x, end = be.y;
            float acc = 0.f;
            int e = beg;
            for (; e + 16 <= end; e += 16) {
                uint_t r[16];
                float  vv[16];
#pragma unroll
                for (int k = 0; k < 16; ++k) r[k] = pedges[e + k];
#pragma unroll
                for (int k = 0; k < 16; ++k)
                    vv[k] = b2f(hb[(size_t)(r[k] & 0xFFFFu) * D + lane]);
#pragma unroll
                for (int k = 0; k < 16; ++k)
                    acc = fmaf(__uint_as_float(r[k] & 0xFFFF0000u), vv[k], acc);
            }
            for (; e + 4 <= end; e += 4) {
                uint_t r[4];
                float  vv[4];
#pragma unroll
                for (int k = 0; k < 4; ++k) r[k] = pedges[e + k];
#pragma unroll
                for (int k = 0; k < 4; ++k)
                    vv[k] = b2f(hb[(size_t)(r[k] & 0xFFFFu) * D + lane]);
#pragma unroll
                for (int k = 0; k < 4; ++k)
                    acc = fmaf(__uint_as_float(r[k] & 0xFFFF0000u), vv[k], acc);
            }
            for (; e < end; ++e) {
                const uint_t r = pedges[e];
                acc = fmaf(__uint_as_float(r & 0xFFFF0000u),
                           b2f(hb[(size_t)(r & 0xFFFFu) * D + lane]), acc);
            }
            nstage[j * D + lane] = f2b(acc);
        }
    }
    __syncthreads();

    // ---- phase 2: waves 0-3, one 16-col tile each ----
    const int nt = wave;
    if (nt >= 4 || node0 >= N_NODES) return;
    const int row16 = lane & 15;
    const int quad  = lane >> 4;

    const size_t abase = (size_t)(node0 + row16) * D + quad * 8;
    const short8 ah0 = *(const short8*)(hb + abase);
    const short8 ah1 = *(const short8*)(hb + abase + 32);
    const ushort_t* sp = nstage + row16 * D + quad * 8;
    const short8 an0 = *(const short8*)sp;
    const short8 an1 = *(const short8*)(sp + 32);

    const int col = nt * 16 + row16;
    const float* wsr = Ws + (size_t)col * D + quad * 8;
    const float* wnr = Wn + (size_t)col * D + quad * 8;
    short8 bw[4];   // ws_k0, ws_k1, wn_k0, wn_k1
#pragma unroll
    for (int f = 0; f < 4; ++f) {
        const float* p = (f < 2 ? wsr : wnr) + (f & 1) * 32;
        const float4 w0 = *(const float4*)p;
        const float4 w1 = *(const float4*)(p + 4);
        short8 bwv;
        bwv[0] = (short)f2b(w0.x); bwv[1] = (short)f2b(w0.y);
        bwv[2] = (short)f2b(w0.z); bwv[3] = (short)f2b(w0.w);
        bwv[4] = (short)f2b(w1.x); bwv[5] = (short)f2b(w1.y);
        bwv[6] = (short)f2b(w1.z); bwv[7] = (short)f2b(w1.w);
        bw[f] = bwv;
    }
    float4v acc = {0.f, 0.f, 0.f, 0.f};
    acc = __builtin_amdgcn_mfma_f32_16x16x32_bf16(ah0, bw[0], acc, 0, 0, 0);
    acc = __builtin_amdgcn_mfma_f32_16x16x32_bf16(ah1, bw[1], acc, 0, 0, 0);
    acc = __builtin_amdgcn_mfma_f32_16x16x32_bf16(an0, bw[2], acc, 0, 0, 0);
    acc = __builtin_amdgcn_mfma_f32_16x16x32_bf16(an1, bw[3], acc, 0, 0, 0);

    const float bias = bs[col] + bn[col];
#pragma unroll
    for (int r = 0; r < 4; ++r) {
        const int m = quad * 4 + r;
        out[(size_t)(node0 + m) * D + col] = fmaxf(acc[r] + bias, 0.f);
    }
}

// ---------------- fallback path (ws too small): fp32 atomic scatter ----------------
__global__ __launch_bounds__(256) void sage_scatter(
    const float* __restrict__ h,
    const int* __restrict__ edge_src,
    const int* __restrict__ edge_dst,
    const float* __restrict__ edge_w,
    float* __restrict__ neigh)
{
    const long long tid = (long long)blockIdx.x * blockDim.x + threadIdx.x;
    const int e = (int)(tid >> 6);
    const int d = (int)(tid & 63);
    if (e >= N_EDGES) return;
    atomicAdd(&neigh[(long long)edge_dst[e] * D + d],
              edge_w[e] * h[(long long)edge_src[e] * D + d]);
}

__global__ __launch_bounds__(256, 2) void linear_f32_kernel(
    const float* __restrict__ h, const float* __restrict__ neigh,
    const float* __restrict__ Ws, const float* __restrict__ bs,
    const float* __restrict__ Wn, const float* __restrict__ bn,
    float* __restrict__ out)
{
    const int lane   = threadIdx.x & 63;
    const int gwave  = (blockIdx.x * blockDim.x + threadIdx.x) >> 6;
    const int nwaves = (gridDim.x * blockDim.x) >> 6;

    float Wsr[D], Wnr[D];
#pragma unroll
    for (int k = 0; k < D; k += 4) {
        const float4 a = *(const float4*)&Ws[(size_t)lane * D + k];
        const float4 b = *(const float4*)&Wn[(size_t)lane * D + k];
        Wsr[k] = a.x; Wsr[k+1] = a.y; Wsr[k+2] = a.z; Wsr[k+3] = a.w;
        Wnr[k] = b.x; Wnr[k+1] = b.y; Wnr[k+2] = b.z; Wnr[k+3] = b.w;
    }
    const float bias = bs[lane] + bn[lane];

    for (int n = gwave; n < N_NODES; n += nwaves) {
        const float hv = h[(size_t)n * D + lane];
        const float nv = neigh[(size_t)n * D + lane];
        float o = bias;
#pragma unroll
        for (int k = 0; k < D; ++k) {
            o = fmaf(lane_bcast(hv, k), Wsr[k], o);
            o = fmaf(lane_bcast(nv, k), Wnr[k], o);
        }
        out[(size_t)n * D + lane] = fmaxf(o, 0.f);
    }
}

extern "C" void kernel_launch(void* const* d_in, const int* in_sizes, int n_in,
                              void* d_out, int out_size, void* d_ws, size_t ws_size,
                              hipStream_t stream)
{
    const float* h        = (const float*)d_in[0];
    const int*   edge_src = (const int*)d_in[1];
    const int*   edge_dst = (const int*)d_in[2];
    const float* edge_w   = (const float*)d_in[3];
    const float* W_self   = (const float*)d_in[4];
    const float* b_self   = (const float*)d_in[5];
    const float* W_neigh  = (const float*)d_in[6];
    const float* b_neigh  = (const float*)d_in[7];
    float*       out      = (float*)d_out;

    // ws layout
    int2*     bedges = (int2*)d_ws;                               // NB*CAP int2
    uint_t*   pedges = (uint_t*)(bedges + (size_t)NB * CAP);      // NB*CAP uint
    int2*     offs2  = (int2*)(pedges + (size_t)NB * CAP);        // N_NODES int2
    ushort_t* hb     = (ushort_t*)(offs2 + N_NODES);              // N*D ushort
    int*      cursor = (int*)(hb + (size_t)N_NODES * D);          // NB
    const size_t needed = (size_t)NB * CAP * 8 + (size_t)NB * CAP * 4
                        + (size_t)N_NODES * 8 + (size_t)N_NODES * D * 2 + NB * 4;

    if (ws_size >= needed) {
        hipMemsetAsync(cursor, 0, NB * sizeof(int), stream);
        bin_h2b_kernel<<<NCHUNKS + CONVB, BT, 0, stream>>>(
            edge_src, edge_dst, edge_w, cursor, bedges, h, hb);
        bucket_csr_kernel<<<NB, CT, 0, stream>>>(cursor, bedges, pedges, offs2);
        gather_linear_kernel<<<(N_NODES + GBLK - 1) / GBLK, 512, 0, stream>>>(
            hb, pedges, offs2, W_self, b_self, W_neigh, b_neigh, out);
    } else {
        float* neigh_fb = (float*)d_ws;
        hipMemsetAsync(neigh_fb, 0, (size_t)N_NODES * D * sizeof(float), stream);
        const long long total = (long long)N_EDGES * 64;
        sage_scatter<<<(int)((total + 255) / 256), 256, 0, stream>>>(
            h, edge_src, edge_dst, edge_w, neigh_fb);
        linear_f32_kernel<<<1024, 256, 0, stream>>>(h, neigh_fb, W_self, b_self,
                                                    W_neigh, b_neigh, out);
    }
}

// Round 4
// 143.305 us; speedup vs baseline: 1.4505x; 1.0832x over previous
//
#include <hip/hip_runtime.h>

#define N_NODES 50000
#define N_EDGES 800000
#define D 64

#define NPB 200                      // nodes per bucket
#define NB  250                      // buckets (NPB*NB == N_NODES)
#define CAP 4096                     // record capacity per bucket (mean 3200, 15.8 sigma)
#define BT  512                      // threads for bin (8 waves)
#define EPT 8                        // edges per thread in bin  -- R16: was 4
#define CHUNK_E (BT * EPT)           // 4096 edges per block
#define NCHUNKS ((N_EDGES + CHUNK_E - 1) / CHUNK_E)   // 196
#define CONVB 256                    // h->bf16 conversion blocks appended to bin grid
#define CT  1024                     // bucket_csr threads (16 waves)
#define GBLK 16                      // nodes per fused gather+linear block (= 1 MFMA tile)

typedef unsigned short ushort_t;
typedef unsigned int   uint_t;
typedef __attribute__((ext_vector_type(8))) short   short8;
typedef __attribute__((ext_vector_type(4))) float   float4v;

// bf16 helpers (RNE down-convert; up-convert is exact)
__device__ __forceinline__ ushort_t f2b(float f) {
    uint_t u = __float_as_uint(f);
    return (ushort_t)((u + 0x7FFFu + ((u >> 16) & 1u)) >> 16);
}
__device__ __forceinline__ float b2f(ushort_t b) {
    return __uint_as_float((uint_t)b << 16);
}
// fp32 bits -> bf16 bits (RNE), kept in the HIGH 16 bits of a uint
__device__ __forceinline__ uint_t rne_hi16(uint_t u) {
    return (u + 0x7FFFu + ((u >> 16) & 1u)) & 0xFFFF0000u;
}
__device__ __forceinline__ float lane_bcast(float v, int l) {
    return __int_as_float(__builtin_amdgcn_readlane(__float_as_int(v), l));
}

// ---------------------------------------------------------------------------
// ws layout (16B-aligned sections):
//   bedges : int2[NB*CAP]     (8.19 MB) bucket-grouped packed records (bin out)
//   pedges : uint[NB*CAP]     (4.10 MB) node-sorted records: src | (w_bf16<<16)
//   offs2  : int2[N_NODES]    (0.4 MB)  per-node (beg,end) into pedges
//   h_bf16 : ushort[N*D]      (6.4 MB)
//   cursor : int[NB]          (memset 0; bin rebases to b*CAP + old)
// Binned record: .x=(src<<8)|local_dst, .y=bits(w).
//
// Cost ledger (R14-R15 post-mortems): measured dur includes the harness's
// 268 MB ws poison fill (~46.5 us, irreducible). Best split (R0): fill 46.5
// + bin ~45 + csr ~4 + gather ~47 + memset/gaps ~3 = 145.
//  - R14: per-node atomic tickets = 50 us standalone (800k atomic-w-return).
//  - R15: 2x chunks (782x256, fewer barriers, more resident chains) LOST
//    10 us -> bin is NOT latency/barrier-bound; cost tracks ticket count
//    and flush fragmentation (both doubled in R15).
//  - R16: halve chunks: 196x512xEPT8. Tickets 98k->49k, flush segments
//    8.2->16.4 records (2-line bursts). Predict bin ~28-32.
//    (R3 bench attempt died to container infra; resubmitted unchanged.)
// ---------------------------------------------------------------------------

// ---------------- K1: bin edges by bucket (blocks < NCHUNKS) + h->bf16 (rest) ----
__global__ __launch_bounds__(BT) void bin_h2b_kernel(
    const int* __restrict__ src, const int* __restrict__ dst,
    const float* __restrict__ w, int* __restrict__ cursor,
    int2* __restrict__ bedges,
    const float* __restrict__ h, ushort_t* __restrict__ hb)
{
    if (blockIdx.x >= NCHUNKS) {
        const int nb = gridDim.x - NCHUNKS;
        for (int i = (blockIdx.x - NCHUNKS) * BT + threadIdx.x;
             i < N_NODES * D / 4; i += nb * BT) {
            const float4 v = ((const float4*)h)[i];
            ushort4 o;
            o.x = f2b(v.x); o.y = f2b(v.y); o.z = f2b(v.z); o.w = f2b(v.w);
            ((ushort4*)hb)[i] = o;
        }
        return;
    }

    __shared__ int lh[NB];
    __shared__ int loff[NB];
    __shared__ int lcur[NB];
    __shared__ int gpos[NB];
    __shared__ int part[256];
    __shared__ int2 stage[CHUNK_E];
    __shared__ unsigned char sbk[CHUNK_E];

    const int t = threadIdx.x;
    for (int i = t; i < NB; i += BT) lh[i] = 0;
    __syncthreads();

    const int base = blockIdx.x * CHUNK_E;
    int   my_b[EPT];
    int   my_p[EPT];
    float my_w[EPT];
#pragma unroll
    for (int k = 0; k < EPT; ++k) {
        const int e = base + k * BT + t;
        if (e < N_EDGES) {
            const int d = dst[e];
            const int b = (unsigned)d / NPB;
            my_b[k] = b;
            my_p[k] = (src[e] << 8) | (d - b * NPB);
            my_w[k] = w[e];
            atomicAdd(&lh[b], 1);
        } else {
            my_b[k] = -1;
        }
    }
    __syncthreads();

    const int v = (t < NB) ? lh[t] : 0;
    if (t < 256) part[t] = v;
    __syncthreads();
    for (int off = 1; off < 256; off <<= 1) {
        int p = 0;
        if (t < 256 && t >= off) p = part[t - off];
        __syncthreads();
        if (t < 256) part[t] += p;
        __syncthreads();
    }
    if (t < NB) { loff[t] = part[t] - v; lcur[t] = part[t] - v; }
    __syncthreads();

#pragma unroll
    for (int k = 0; k < EPT; ++k) {
        if (my_b[k] >= 0) {
            const int p = atomicAdd(&lcur[my_b[k]], 1);
            stage[p] = make_int2(my_p[k], __float_as_int(my_w[k]));
            sbk[p] = (unsigned char)my_b[k];
        }
    }
    __syncthreads();

    if (t < NB && lh[t] > 0)
        gpos[t] = t * CAP + atomicAdd(&cursor[t], lh[t]);
    __syncthreads();

    const int tot = min(N_EDGES - base, CHUNK_E);
    for (int s = t; s < tot; s += BT) {
        const int b = sbk[s];
        bedges[gpos[b] + (s - loff[b])] = stage[s];
    }
}

// ---------------- K2: per-bucket node-exact CSR -> packed 4-B records ----------
__global__ __launch_bounds__(CT) void bucket_csr_kernel(
    const int* __restrict__ cursor, const int2* __restrict__ bedges,
    uint_t* __restrict__ pedges, int2* __restrict__ offs2)
{
    __shared__ int    lcur[NPB];
    __shared__ int    part[256];
    __shared__ uint_t stage[CAP];   // 16 KB

    const int b   = blockIdx.x;
    const int t   = threadIdx.x;
    const int gb  = b * CAP;
    const int cnt = min(cursor[b], CAP);

    // per-node histogram
    if (t < NPB) lcur[t] = 0;
    __syncthreads();
    for (int e = t; e < cnt; e += CT)
        atomicAdd(&lcur[bedges[gb + e].x & 255], 1);
    __syncthreads();

    // exclusive scan of NPB counts (first 256 threads)
    const int v = (t < NPB) ? lcur[t] : 0;
    if (t < 256) part[t] = v;
    __syncthreads();
    for (int off = 1; off < 256; off <<= 1) {
        int p = 0;
        if (t < 256 && t >= off) p = part[t - off];
        __syncthreads();
        if (t < 256) part[t] += p;
        __syncthreads();
    }
    if (t < NPB) {
        const int ex = part[t] - v;
        lcur[t] = ex;
        offs2[b * NPB + t] = make_int2(gb + ex, gb + ex + v);
    }
    __syncthreads();

    // position via LDS atomics, scatter PACKED into LDS stage
    for (int e = t; e < cnt; e += CT) {
        const int2 r = bedges[gb + e];
        const int p = atomicAdd(&lcur[r.x & 255], 1);
        stage[p] = (uint_t)(r.x >> 8) | rne_hi16((uint_t)r.y);
    }
    __syncthreads();
    // fully coalesced flush to pedges
    for (int s = t; s < cnt; s += CT)
        pedges[gb + s] = stage[s];
}

// ---------------- K3: fused gather (8 waves x 2 nodes, 16-deep) + MFMA linear ----
__global__ __launch_bounds__(512) void gather_linear_kernel(
    const ushort_t* __restrict__ hb, const uint_t* __restrict__ pedges,
    const int2* __restrict__ offs2,
    const float* __restrict__ Ws, const float* __restrict__ bs,
    const float* __restrict__ Wn, const float* __restrict__ bn,
    float* __restrict__ out)
{
    __shared__ ushort_t nstage[GBLK * D];   // 2 KB

    const int wave  = threadIdx.x >> 6;     // 0..7
    const int lane  = threadIdx.x & 63;
    const int node0 = blockIdx.x * GBLK;

    // ---- phase 1: 2 nodes per wave, 16-deep MLP ----
#pragma unroll
    for (int jj = 0; jj < 2; ++jj) {
        const int j = wave * 2 + jj;        // node-in-block 0..15
        const int node = node0 + j;
        if (node < N_NODES) {
            const int2 be = offs2[node];
            const int beg = be.x, end = be.y;
            float acc = 0.f;
            int e = beg;
            for (; e + 16 <= end; e += 16) {
                uint_t r[16];
                float  vv[16];
#pragma unroll
                for (int k = 0; k < 16; ++k) r[k] = pedges[e + k];
#pragma unroll
                for (int k = 0; k < 16; ++k)
                    vv[k] = b2f(hb[(size_t)(r[k] & 0xFFFFu) * D + lane]);
#pragma unroll
                for (int k = 0; k < 16; ++k)
                    acc = fmaf(__uint_as_float(r[k] & 0xFFFF0000u), vv[k], acc);
            }
            for (; e + 4 <= end; e += 4) {
                uint_t r[4];
                float  vv[4];
#pragma unroll
                for (int k = 0; k < 4; ++k) r[k] = pedges[e + k];
#pragma unroll
                for (int k = 0; k < 4; ++k)
                    vv[k] = b2f(hb[(size_t)(r[k] & 0xFFFFu) * D + lane]);
#pragma unroll
                for (int k = 0; k < 4; ++k)
                    acc = fmaf(__uint_as_float(r[k] & 0xFFFF0000u), vv[k], acc);
            }
            for (; e < end; ++e) {
                const uint_t r = pedges[e];
                acc = fmaf(__uint_as_float(r & 0xFFFF0000u),
                           b2f(hb[(size_t)(r & 0xFFFFu) * D + lane]), acc);
            }
            nstage[j * D + lane] = f2b(acc);
        }
    }
    __syncthreads();

    // ---- phase 2: waves 0-3, one 16-col tile each ----
    const int nt = wave;
    if (nt >= 4 || node0 >= N_NODES) return;
    const int row16 = lane & 15;
    const int quad  = lane >> 4;

    const size_t abase = (size_t)(node0 + row16) * D + quad * 8;
    const short8 ah0 = *(const short8*)(hb + abase);
    const short8 ah1 = *(const short8*)(hb + abase + 32);
    const ushort_t* sp = nstage + row16 * D + quad * 8;
    const short8 an0 = *(const short8*)sp;
    const short8 an1 = *(const short8*)(sp + 32);

    const int col = nt * 16 + row16;
    const float* wsr = Ws + (size_t)col * D + quad * 8;
    const float* wnr = Wn + (size_t)col * D + quad * 8;
    short8 bw[4];   // ws_k0, ws_k1, wn_k0, wn_k1
#pragma unroll
    for (int f = 0; f < 4; ++f) {
        const float* p = (f < 2 ? wsr : wnr) + (f & 1) * 32;
        const float4 w0 = *(const float4*)p;
        const float4 w1 = *(const float4*)(p + 4);
        short8 bwv;
        bwv[0] = (short)f2b(w0.x); bwv[1] = (short)f2b(w0.y);
        bwv[2] = (short)f2b(w0.z); bwv[3] = (short)f2b(w0.w);
        bwv[4] = (short)f2b(w1.x); bwv[5] = (short)f2b(w1.y);
        bwv[6] = (short)f2b(w1.z); bwv[7] = (short)f2b(w1.w);
        bw[f] = bwv;
    }
    float4v acc = {0.f, 0.f, 0.f, 0.f};
    acc = __builtin_amdgcn_mfma_f32_16x16x32_bf16(ah0, bw[0], acc, 0, 0, 0);
    acc = __builtin_amdgcn_mfma_f32_16x16x32_bf16(ah1, bw[1], acc, 0, 0, 0);
    acc = __builtin_amdgcn_mfma_f32_16x16x32_bf16(an0, bw[2], acc, 0, 0, 0);
    acc = __builtin_amdgcn_mfma_f32_16x16x32_bf16(an1, bw[3], acc, 0, 0, 0);

    const float bias = bs[col] + bn[col];
#pragma unroll
    for (int r = 0; r < 4; ++r) {
        const int m = quad * 4 + r;
        out[(size_t)(node0 + m) * D + col] = fmaxf(acc[r] + bias, 0.f);
    }
}

// ---------------- fallback path (ws too small): fp32 atomic scatter ----------------
__global__ __launch_bounds__(256) void sage_scatter(
    const float* __restrict__ h,
    const int* __restrict__ edge_src,
    const int* __restrict__ edge_dst,
    const float* __restrict__ edge_w,
    float* __restrict__ neigh)
{
    const long long tid = (long long)blockIdx.x * blockDim.x + threadIdx.x;
    const int e = (int)(tid >> 6);
    const int d = (int)(tid & 63);
    if (e >= N_EDGES) return;
    atomicAdd(&neigh[(long long)edge_dst[e] * D + d],
              edge_w[e] * h[(long long)edge_src[e] * D + d]);
}

__global__ __launch_bounds__(256, 2) void linear_f32_kernel(
    const float* __restrict__ h, const float* __restrict__ neigh,
    const float* __restrict__ Ws, const float* __restrict__ bs,
    const float* __restrict__ Wn, const float* __restrict__ bn,
    float* __restrict__ out)
{
    const int lane   = threadIdx.x & 63;
    const int gwave  = (blockIdx.x * blockDim.x + threadIdx.x) >> 6;
    const int nwaves = (gridDim.x * blockDim.x) >> 6;

    float Wsr[D], Wnr[D];
#pragma unroll
    for (int k = 0; k < D; k += 4) {
        const float4 a = *(const float4*)&Ws[(size_t)lane * D + k];
        const float4 b = *(const float4*)&Wn[(size_t)lane * D + k];
        Wsr[k] = a.x; Wsr[k+1] = a.y; Wsr[k+2] = a.z; Wsr[k+3] = a.w;
        Wnr[k] = b.x; Wnr[k+1] = b.y; Wnr[k+2] = b.z; Wnr[k+3] = b.w;
    }
    const float bias = bs[lane] + bn[lane];

    for (int n = gwave; n < N_NODES; n += nwaves) {
        const float hv = h[(size_t)n * D + lane];
        const float nv = neigh[(size_t)n * D + lane];
        float o = bias;
#pragma unroll
        for (int k = 0; k < D; ++k) {
            o = fmaf(lane_bcast(hv, k), Wsr[k], o);
            o = fmaf(lane_bcast(nv, k), Wnr[k], o);
        }
        out[(size_t)n * D + lane] = fmaxf(o, 0.f);
    }
}

extern "C" void kernel_launch(void* const* d_in, const int* in_sizes, int n_in,
                              void* d_out, int out_size, void* d_ws, size_t ws_size,
                              hipStream_t stream)
{
    const float* h        = (const float*)d_in[0];
    const int*   edge_src = (const int*)d_in[1];
    const int*   edge_dst = (const int*)d_in[2];
    const float* edge_w   = (const float*)d_in[3];
    const float* W_self   = (const float*)d_in[4];
    const float* b_self   = (const float*)d_in[5];
    const float* W_neigh  = (const float*)d_in[6];
    const float* b_neigh  = (const float*)d_in[7];
    float*       out      = (float*)d_out;

    // ws layout
    int2*     bedges = (int2*)d_ws;                               // NB*CAP int2
    uint_t*   pedges = (uint_t*)(bedges + (size_t)NB * CAP);      // NB*CAP uint
    int2*     offs2  = (int2*)(pedges + (size_t)NB * CAP);        // N_NODES int2
    ushort_t* hb     = (ushort_t*)(offs2 + N_NODES);              // N*D ushort
    int*      cursor = (int*)(hb + (size_t)N_NODES * D);          // NB
    const size_t needed = (size_t)NB * CAP * 8 + (size_t)NB * CAP * 4
                        + (size_t)N_NODES * 8 + (size_t)N_NODES * D * 2 + NB * 4;

    if (ws_size >= needed) {
        hipMemsetAsync(cursor, 0, NB * sizeof(int), stream);
        bin_h2b_kernel<<<NCHUNKS + CONVB, BT, 0, stream>>>(
            edge_src, edge_dst, edge_w, cursor, bedges, h, hb);
        bucket_csr_kernel<<<NB, CT, 0, stream>>>(cursor, bedges, pedges, offs2);
        gather_linear_kernel<<<(N_NODES + GBLK - 1) / GBLK, 512, 0, stream>>>(
            hb, pedges, offs2, W_self, b_self, W_neigh, b_neigh, out);
    } else {
        float* neigh_fb = (float*)d_ws;
        hipMemsetAsync(neigh_fb, 0, (size_t)N_NODES * D * sizeof(float), stream);
        const long long total = (long long)N_EDGES * 64;
        sage_scatter<<<(int)((total + 255) / 256), 256, 0, stream>>>(
            h, edge_src, edge_dst, edge_w, neigh_fb);
        linear_f32_kernel<<<1024, 256, 0, stream>>>(h, neigh_fb, W_self, b_self,
                                                    W_neigh, b_neigh, out);
    }
}

// Round 5
// 142.192 us; speedup vs baseline: 1.4618x; 1.0078x over previous
//
#include <hip/hip_runtime.h>

#define N_NODES 50000
#define N_EDGES 800000
#define D 64

#define NPB 200                      // nodes per bucket
#define NB  250                      // buckets (NPB*NB == N_NODES)
#define CAP 4096                     // record capacity per bucket (mean 3200, 15.8 sigma)
#define BT  512                      // threads for bin (8 waves)
#define EPT 8                        // edges per thread in bin (R16 best)
#define CHUNK_E (BT * EPT)           // 4096 edges per block
#define NCHUNKS ((N_EDGES + CHUNK_E - 1) / CHUNK_E)   // 196
#define CONVB 256                    // h->bf16 conversion blocks appended to bin grid
#define CT  1024                     // csr_gather threads (16 waves)
#define NTILE ((NPB + 15) / 16)      // 13 MFMA row-tiles per bucket (last is half)

typedef unsigned short ushort_t;
typedef unsigned int   uint_t;
typedef __attribute__((ext_vector_type(8))) short   short8;
typedef __attribute__((ext_vector_type(4))) float   float4v;

// bf16 helpers (RNE down-convert; up-convert is exact)
__device__ __forceinline__ ushort_t f2b(float f) {
    uint_t u = __float_as_uint(f);
    return (ushort_t)((u + 0x7FFFu + ((u >> 16) & 1u)) >> 16);
}
__device__ __forceinline__ float b2f(ushort_t b) {
    return __uint_as_float((uint_t)b << 16);
}
// fp32 bits -> bf16 bits (RNE), kept in the HIGH 16 bits of a uint
__device__ __forceinline__ uint_t rne_hi16(uint_t u) {
    return (u + 0x7FFFu + ((u >> 16) & 1u)) & 0xFFFF0000u;
}
__device__ __forceinline__ float lane_bcast(float v, int l) {
    return __int_as_float(__builtin_amdgcn_readlane(__float_as_int(v), l));
}

// ---------------------------------------------------------------------------
// ws layout (16B-aligned sections):
//   bedges : int2[NB*CAP]     (8.19 MB) bucket-grouped packed records (bin out)
//   h_bf16 : ushort[N*D]      (6.4 MB)
//   cursor : int[NB]          (memset 0; bin rebases to b*CAP + old)
// Binned record: .x=(src<<8)|local_dst, .y=bits(w).
//
// Cost ledger (R14-R16 post-mortems): measured dur includes the harness's
// 268 MB ws poison fill (~46.5 us, irreducible). R16 split (inferred):
// fill 46.5 + bin ~42 + csr ~4 + gather ~47.4 + memset/gaps ~3 = 143.3.
//  - R14: per-node atomic tickets = 50 us standalone (800k atomic-w-return).
//  - R15: 2x chunks LOST 10 us (fragmentation+tickets doubled).
//  - R16: 0.5x chunks gained only 2 us -> bin cost is asymmetrically flat;
//    mechanism UNCONFIRMED (first-principles says ~10 us). bin/csr have
//    never appeared in top-5: ledger is inference, not measurement.
//  - R17 (this): fuse csr+gather into one kernel (sort in LDS -> gather
//    from LDS -> MFMA). Kills pedges round-trip (6.8 MB), offs2, one
//    launch, and gather's 1.45x wave imbalance (fused: 1.18x). Side
//    effect: 3-kernel chain makes every kernel's duration observable in
//    top-5 next round -> ground-truth ledger.
// ---------------------------------------------------------------------------

// ---------------- K1: bin edges by bucket (blocks < NCHUNKS) + h->bf16 (rest) ----
__global__ __launch_bounds__(BT) void bin_h2b_kernel(
    const int* __restrict__ src, const int* __restrict__ dst,
    const float* __restrict__ w, int* __restrict__ cursor,
    int2* __restrict__ bedges,
    const float* __restrict__ h, ushort_t* __restrict__ hb)
{
    if (blockIdx.x >= NCHUNKS) {
        const int nb = gridDim.x - NCHUNKS;
        for (int i = (blockIdx.x - NCHUNKS) * BT + threadIdx.x;
             i < N_NODES * D / 4; i += nb * BT) {
            const float4 v = ((const float4*)h)[i];
            ushort4 o;
            o.x = f2b(v.x); o.y = f2b(v.y); o.z = f2b(v.z); o.w = f2b(v.w);
            ((ushort4*)hb)[i] = o;
        }
        return;
    }

    __shared__ int lh[NB];
    __shared__ int loff[NB];
    __shared__ int lcur[NB];
    __shared__ int gpos[NB];
    __shared__ int part[256];
    __shared__ int2 stage[CHUNK_E];
    __shared__ unsigned char sbk[CHUNK_E];

    const int t = threadIdx.x;
    for (int i = t; i < NB; i += BT) lh[i] = 0;
    __syncthreads();

    const int base = blockIdx.x * CHUNK_E;
    int   my_b[EPT];
    int   my_p[EPT];
    float my_w[EPT];
#pragma unroll
    for (int k = 0; k < EPT; ++k) {
        const int e = base + k * BT + t;
        if (e < N_EDGES) {
            const int d = dst[e];
            const int b = (unsigned)d / NPB;
            my_b[k] = b;
            my_p[k] = (src[e] << 8) | (d - b * NPB);
            my_w[k] = w[e];
            atomicAdd(&lh[b], 1);
        } else {
            my_b[k] = -1;
        }
    }
    __syncthreads();

    const int v = (t < NB) ? lh[t] : 0;
    if (t < 256) part[t] = v;
    __syncthreads();
    for (int off = 1; off < 256; off <<= 1) {
        int p = 0;
        if (t < 256 && t >= off) p = part[t - off];
        __syncthreads();
        if (t < 256) part[t] += p;
        __syncthreads();
    }
    if (t < NB) { loff[t] = part[t] - v; lcur[t] = part[t] - v; }
    __syncthreads();

#pragma unroll
    for (int k = 0; k < EPT; ++k) {
        if (my_b[k] >= 0) {
            const int p = atomicAdd(&lcur[my_b[k]], 1);
            stage[p] = make_int2(my_p[k], __float_as_int(my_w[k]));
            sbk[p] = (unsigned char)my_b[k];
        }
    }
    __syncthreads();

    if (t < NB && lh[t] > 0)
        gpos[t] = t * CAP + atomicAdd(&cursor[t], lh[t]);
    __syncthreads();

    const int tot = min(N_EDGES - base, CHUNK_E);
    for (int s = t; s < tot; s += BT) {
        const int b = sbk[s];
        bedges[gpos[b] + (s - loff[b])] = stage[s];
    }
}

// ---------------- K2: fused per-bucket sort + gather + MFMA linear ----------
// Phase A: node-exact counting sort of the bucket's records into LDS stage.
// Phase B: 16 waves x ~12.5 nodes, register-accumulate from LDS records
//          (wave imbalance 1.18x vs old gather's 1.45x).
// Phase C: 13x4 MFMA 16x16 tile tasks; last row-tile half-masked at store.
__global__ __launch_bounds__(CT) void csr_gather_kernel(
    const int* __restrict__ cursor, const int2* __restrict__ bedges,
    const ushort_t* __restrict__ hb,
    const float* __restrict__ Ws, const float* __restrict__ bs,
    const float* __restrict__ Wn, const float* __restrict__ bn,
    float* __restrict__ out)
{
    __shared__ int      offs[NPB + 1];
    __shared__ int      lcur[NPB];
    __shared__ int      part[256];
    __shared__ __align__(16) uint_t   stage[CAP];              // 16 KB
    __shared__ __align__(16) ushort_t nstage[NTILE * 16 * D];  // 26 KB

    const int b   = blockIdx.x;
    const int t   = threadIdx.x;
    const int gb  = b * CAP;
    const int cnt = min(cursor[b], CAP);

    // ---- phase A: per-node histogram + scan + positioned scatter into LDS ----
    if (t < NPB) lcur[t] = 0;
    __syncthreads();
    for (int e = t; e < cnt; e += CT)
        atomicAdd(&lcur[bedges[gb + e].x & 255], 1);
    __syncthreads();

    const int v = (t < NPB) ? lcur[t] : 0;
    if (t < 256) part[t] = v;
    __syncthreads();
    for (int off = 1; off < 256; off <<= 1) {
        int p = 0;
        if (t < 256 && t >= off) p = part[t - off];
        __syncthreads();
        if (t < 256) part[t] += p;
        __syncthreads();
    }
    if (t < NPB) {
        const int ex = part[t] - v;
        offs[t] = ex;
        lcur[t] = ex;
    }
    if (t == 0) offs[NPB] = cnt;
    // zero nstage pad rows (200..207) so tile 13's A-neigh reads are defined
    if (t < (NTILE * 16 - NPB) * D) nstage[NPB * D + t] = 0;
    __syncthreads();

    for (int e = t; e < cnt; e += CT) {
        const int2 r = bedges[gb + e];
        const int p = atomicAdd(&lcur[r.x & 255], 1);
        stage[p] = (uint_t)(r.x >> 8) | rne_hi16((uint_t)r.y);
    }
    __syncthreads();

    // ---- phase B: per-node gather-accumulate from LDS records ----
    const int wave = t >> 6;
    const int lane = t & 63;
    const int nbeg = wave * 12 + min(wave, 8);      // waves 0-7: 13 nodes, 8-15: 12
    const int ncnt = 12 + (wave < 8 ? 1 : 0);
    for (int ni = 0; ni < ncnt; ++ni) {
        const int n   = nbeg + ni;
        const int beg = offs[n], end = offs[n + 1];
        float acc = 0.f;
        int e = beg;
        for (; e + 8 <= end; e += 8) {
            uint_t r[8];
            float  vv[8];
#pragma unroll
            for (int k = 0; k < 8; ++k) r[k] = stage[e + k];
#pragma unroll
            for (int k = 0; k < 8; ++k)
                vv[k] = b2f(hb[(size_t)(r[k] & 0xFFFFu) * D + lane]);
#pragma unroll
            for (int k = 0; k < 8; ++k)
                acc = fmaf(__uint_as_float(r[k] & 0xFFFF0000u), vv[k], acc);
        }
        for (; e < end; ++e) {
            const uint_t r = stage[e];
            acc = fmaf(__uint_as_float(r & 0xFFFF0000u),
                       b2f(hb[(size_t)(r & 0xFFFFu) * D + lane]), acc);
        }
        nstage[n * D + lane] = f2b(acc);
    }
    __syncthreads();

    // ---- phase C: MFMA linear, NTILE*4 = 52 tile tasks over 16 waves ----
    const int node0b = b * NPB;
    const int row16  = lane & 15;
    const int quad   = lane >> 4;
    for (int task = wave; task < NTILE * 4; task += 16) {
        const int m  = task >> 2;       // row tile 0..12
        const int nt = task & 3;        // col tile 0..3
        const int arow = m * 16 + row16;

        // A-self rows: node0b+arow may overrun the bucket by <=7 rows for
        // m==12; those reads land in the cursor section of ws (safe) and
        // their outputs are store-masked below.
        const size_t abase = (size_t)(node0b + arow) * D + quad * 8;
        const short8 ah0 = *(const short8*)(hb + abase);
        const short8 ah1 = *(const short8*)(hb + abase + 32);
        const ushort_t* sp = nstage + arow * D + quad * 8;
        const short8 an0 = *(const short8*)sp;
        const short8 an1 = *(const short8*)(sp + 32);

        const int col = nt * 16 + row16;
        const float* wsr = Ws + (size_t)col * D + quad * 8;
        const float* wnr = Wn + (size_t)col * D + quad * 8;
        short8 bw[4];   // ws_k0, ws_k1, wn_k0, wn_k1
#pragma unroll
        for (int f = 0; f < 4; ++f) {
            const float* p = (f < 2 ? wsr : wnr) + (f & 1) * 32;
            const float4 w0 = *(const float4*)p;
            const float4 w1 = *(const float4*)(p + 4);
            short8 bwv;
            bwv[0] = (short)f2b(w0.x); bwv[1] = (short)f2b(w0.y);
            bwv[2] = (short)f2b(w0.z); bwv[3] = (short)f2b(w0.w);
            bwv[4] = (short)f2b(w1.x); bwv[5] = (short)f2b(w1.y);
            bwv[6] = (short)f2b(w1.z); bwv[7] = (short)f2b(w1.w);
            bw[f] = bwv;
        }
        float4v acc = {0.f, 0.f, 0.f, 0.f};
        acc = __builtin_amdgcn_mfma_f32_16x16x32_bf16(ah0, bw[0], acc, 0, 0, 0);
        acc = __builtin_amdgcn_mfma_f32_16x16x32_bf16(ah1, bw[1], acc, 0, 0, 0);
        acc = __builtin_amdgcn_mfma_f32_16x16x32_bf16(an0, bw[2], acc, 0, 0, 0);
        acc = __builtin_amdgcn_mfma_f32_16x16x32_bf16(an1, bw[3], acc, 0, 0, 0);

        const float bias = bs[col] + bn[col];
#pragma unroll
        for (int r = 0; r < 4; ++r) {
            const int mr = m * 16 + quad * 4 + r;   // row within bucket
            if (mr < NPB)
                out[(size_t)(node0b + mr) * D + col] = fmaxf(acc[r] + bias, 0.f);
        }
    }
}

// ---------------- fallback path (ws too small): fp32 atomic scatter ----------------
__global__ __launch_bounds__(256) void sage_scatter(
    const float* __restrict__ h,
    const int* __restrict__ edge_src,
    const int* __restrict__ edge_dst,
    const float* __restrict__ edge_w,
    float* __restrict__ neigh)
{
    const long long tid = (long long)blockIdx.x * blockDim.x + threadIdx.x;
    const int e = (int)(tid >> 6);
    const int d = (int)(tid & 63);
    if (e >= N_EDGES) return;
    atomicAdd(&neigh[(long long)edge_dst[e] * D + d],
              edge_w[e] * h[(long long)edge_src[e] * D + d]);
}

__global__ __launch_bounds__(256, 2) void linear_f32_kernel(
    const float* __restrict__ h, const float* __restrict__ neigh,
    const float* __restrict__ Ws, const float* __restrict__ bs,
    const float* __restrict__ Wn, const float* __restrict__ bn,
    float* __restrict__ out)
{
    const int lane   = threadIdx.x & 63;
    const int gwave  = (blockIdx.x * blockDim.x + threadIdx.x) >> 6;
    const int nwaves = (gridDim.x * blockDim.x) >> 6;

    float Wsr[D], Wnr[D];
#pragma unroll
    for (int k = 0; k < D; k += 4) {
        const float4 a = *(const float4*)&Ws[(size_t)lane * D + k];
        const float4 b = *(const float4*)&Wn[(size_t)lane * D + k];
        Wsr[k] = a.x; Wsr[k+1] = a.y; Wsr[k+2] = a.z; Wsr[k+3] = a.w;
        Wnr[k] = b.x; Wnr[k+1] = b.y; Wnr[k+2] = b.z; Wnr[k+3] = b.w;
    }
    const float bias = bs[lane] + bn[lane];

    for (int n = gwave; n < N_NODES; n += nwaves) {
        const float hv = h[(size_t)n * D + lane];
        const float nv = neigh[(size_t)n * D + lane];
        float o = bias;
#pragma unroll
        for (int k = 0; k < D; ++k) {
            o = fmaf(lane_bcast(hv, k), Wsr[k], o);
            o = fmaf(lane_bcast(nv, k), Wnr[k], o);
        }
        out[(size_t)n * D + lane] = fmaxf(o, 0.f);
    }
}

extern "C" void kernel_launch(void* const* d_in, const int* in_sizes, int n_in,
                              void* d_out, int out_size, void* d_ws, size_t ws_size,
                              hipStream_t stream)
{
    const float* h        = (const float*)d_in[0];
    const int*   edge_src = (const int*)d_in[1];
    const int*   edge_dst = (const int*)d_in[2];
    const float* edge_w   = (const float*)d_in[3];
    const float* W_self   = (const float*)d_in[4];
    const float* b_self   = (const float*)d_in[5];
    const float* W_neigh  = (const float*)d_in[6];
    const float* b_neigh  = (const float*)d_in[7];
    float*       out      = (float*)d_out;

    // ws layout
    int2*     bedges = (int2*)d_ws;                               // NB*CAP int2
    ushort_t* hb     = (ushort_t*)(bedges + (size_t)NB * CAP);    // N*D ushort
    int*      cursor = (int*)(hb + (size_t)N_NODES * D);          // NB
    const size_t needed = (size_t)NB * CAP * 8 + (size_t)N_NODES * D * 2 + NB * 4;

    if (ws_size >= needed) {
        hipMemsetAsync(cursor, 0, NB * sizeof(int), stream);
        bin_h2b_kernel<<<NCHUNKS + CONVB, BT, 0, stream>>>(
            edge_src, edge_dst, edge_w, cursor, bedges, h, hb);
        csr_gather_kernel<<<NB, CT, 0, stream>>>(
            cursor, bedges, hb, W_self, b_self, W_neigh, b_neigh, out);
    } else {
        float* neigh_fb = (float*)d_ws;
        hipMemsetAsync(neigh_fb, 0, (size_t)N_NODES * D * sizeof(float), stream);
        const long long total = (long long)N_EDGES * 64;
        sage_scatter<<<(int)((total + 255) / 256), 256, 0, stream>>>(
            h, edge_src, edge_dst, edge_w, neigh_fb);
        linear_f32_kernel<<<1024, 256, 0, stream>>>(h, neigh_fb, W_self, b_self,
                                                    W_neigh, b_neigh, out);
    }
}